// Round 12
// baseline (5073.469 us; speedup 1.0000x reference)
//
#include <hip/hip_runtime.h>
#include <math.h>

#define NN 5000
#define TT 100
#define IND 32
#define FEATD 64
#define HIDD 64
#define OUTD 8
#define NHEADS 4
#define EE 160000
#define FIN 72
#define NHC 256     // HEADS*HID
#define QKV_B 625   // NN/8 qkv blocks in K2
#define LSTM_B 625  // NN/8 lstm blocks in K2

typedef float floatx2 __attribute__((ext_vector_type(2)));

__device__ __forceinline__ float fsig(float x){ return 1.f/(1.f+__expf(-x)); }
__device__ __forceinline__ float ftanh(float x){ return 1.f - 2.f/(__expf(2.f*x)+1.f); }
__device__ __forceinline__ float fsoftplus(float x){ return (x>20.f)? x : log1pf(__expf(x)); }

// ---------------- CSR build ----------------
__global__ __launch_bounds__(256) void count_edges(const int* __restrict__ dst,
                                                   int* __restrict__ cnt){
    int e = blockIdx.x*256 + threadIdx.x;
    if (e < EE) atomicAdd(&cnt[dst[e]], 1);
}

#define SCAN_N 5120
__global__ __launch_bounds__(1024) void scan_csr(const int* __restrict__ cnt,
                                                 int* __restrict__ row_ptr,
                                                 int* __restrict__ cursor){
    __shared__ int sa[SCAN_N];
    __shared__ int sb[SCAN_N];
    int tid = threadIdx.x;
    for (int i=tid;i<SCAN_N;i+=1024) sa[i] = (i<NN)?cnt[i]:0;
    __syncthreads();
    int *s=sa, *d=sb;
    for (int off=1; off<SCAN_N; off<<=1){
        for (int i=tid;i<SCAN_N;i+=1024){
            int v = s[i];
            if (i>=off) v += s[i-off];
            d[i] = v;
        }
        __syncthreads();
        int* t=s; s=d; d=t;
    }
    for (int i=tid;i<=NN;i+=1024){
        int excl = (i==0)?0:s[i-1];
        row_ptr[i] = excl;
        if (i<NN) cursor[i] = excl;
    }
}

__global__ __launch_bounds__(256) void fill_edges(const int* __restrict__ src,
                                                  const int* __restrict__ dst,
                                                  int* __restrict__ cursor,
                                                  int* __restrict__ col){
    int e = blockIdx.x*256 + threadIdx.x;
    if (e < EE){
        int dn = dst[e];
        int pos = atomicAdd(&cursor[dn], 1);
        col[pos] = src[e];
    }
}

// ---------------- K1: attn(step ts) ----------------
// Verbatim r10/r11 attn: 2 nodes x 2 waves per block, dual no-max fp8
// chains, depth-2 prefetch, one 8B load/lane/edge (kv table 2.56MB,
// L2-resident/XCD). No running max is exact: scores |q.k/8| << 80.
// Tail: zero-filled buffers + wave-uniform -INF mask.
#define LOADKV(e) (*reinterpret_cast<const uint2*>(kv + (size_t)col[(e)]*512 + lane*8))
__global__ __launch_bounds__(256) void attn_step(
    const float* __restrict__ q,
    const unsigned char* __restrict__ kv,
    const float* __restrict__ sk,
    const int* __restrict__ row_ptr,
    const int* __restrict__ col,
    const float* __restrict__ Wmlp,
    float* __restrict__ theta,
    float* __restrict__ out,
    int ts)
{
    __shared__ float mrg[2][5][64];
    int tid = threadIdx.x;
    int wvid = tid >> 6;
    int lane = tid & 63;
    int ln   = wvid >> 1;
    int half = wvid & 1;
    int n = blockIdx.x*2 + ln;
    int e0 = row_ptr[n], e1 = row_ptr[n+1];
    float4 qv = *reinterpret_cast<const float4*>(q + n*NHC + lane*4);
    qv.x *= 0.125f; qv.y *= 0.125f; qv.z *= 0.125f; qv.w *= 0.125f;

    float denA=0.f, denB=0.f;
    float aA0=0.f, aA1=0.f, aA2=0.f, aA3=0.f;
    float aB0=0.f, aB1=0.f, aB2=0.f, aB3=0.f;

    const uint2 zv = {0u,0u};
    uint2 bA0=zv, bA1=zv, bB0=zv, bB1=zv;
    int base = e0 + half;
    if (base     < e1) bA0 = LOADKV(base);
    if (base + 2 < e1) bB0 = LOADKV(base+2);
    if (base + 4 < e1) bA1 = LOADKV(base+4);
    if (base + 6 < e1) bB1 = LOADKV(base+6);
    for (int e = base; e < e1; e += 4){
        uint2 uA = bA0; bA0 = bA1; bA1 = zv;
        uint2 uB = bB0; bB0 = bB1; bB1 = zv;
        if (e + 8  < e1) bA1 = LOADKV(e+8);
        if (e + 10 < e1) bB1 = LOADKV(e+10);

        floatx2 kA0 = __builtin_amdgcn_cvt_pk_f32_fp8(uA.x, false);
        floatx2 kA1 = __builtin_amdgcn_cvt_pk_f32_fp8(uA.x, true);
        floatx2 kB0 = __builtin_amdgcn_cvt_pk_f32_fp8(uB.x, false);
        floatx2 kB1 = __builtin_amdgcn_cvt_pk_f32_fp8(uB.x, true);
        float pA = qv.x*kA0[0] + qv.y*kA0[1] + qv.z*kA1[0] + qv.w*kA1[1];
        float pB = qv.x*kB0[0] + qv.y*kB0[1] + qv.z*kB1[0] + qv.w*kB1[1];
        pA += __shfl_xor(pA,1); pB += __shfl_xor(pB,1);
        pA += __shfl_xor(pA,2); pB += __shfl_xor(pB,2);
        pA += __shfl_xor(pA,4); pB += __shfl_xor(pB,4);
        pA += __shfl_xor(pA,8); pB += __shfl_xor(pB,8);

        float eA = __expf(pA);
        float eB = __expf((e + 2 < e1) ? pB : -INFINITY);
        floatx2 vA0 = __builtin_amdgcn_cvt_pk_f32_fp8(uA.y, false);
        floatx2 vA1 = __builtin_amdgcn_cvt_pk_f32_fp8(uA.y, true);
        floatx2 vB0 = __builtin_amdgcn_cvt_pk_f32_fp8(uB.y, false);
        floatx2 vB1 = __builtin_amdgcn_cvt_pk_f32_fp8(uB.y, true);
        denA += eA;
        aA0 = fmaf(eA, vA0[0], aA0);
        aA1 = fmaf(eA, vA0[1], aA1);
        aA2 = fmaf(eA, vA1[0], aA2);
        aA3 = fmaf(eA, vA1[1], aA3);
        denB += eB;
        aB0 = fmaf(eB, vB0[0], aB0);
        aB1 = fmaf(eB, vB0[1], aB1);
        aB2 = fmaf(eB, vB1[0], aB2);
        aB3 = fmaf(eB, vB1[1], aB3);
    }
    float denom = denA + denB;
    float ax = aA0 + aB0;
    float ay = aA1 + aB1;
    float az = aA2 + aB2;
    float aw = aA3 + aB3;

    if (half == 1){
        mrg[ln][0][lane]=denom;
        mrg[ln][1][lane]=ax; mrg[ln][2][lane]=ay;
        mrg[ln][3][lane]=az; mrg[ln][4][lane]=aw;
    }
    __syncthreads();
    if (half == 1) return;

    denom += mrg[ln][0][lane];
    ax += mrg[ln][1][lane];
    ay += mrg[ln][2][lane];
    az += mrg[ln][3][lane];
    aw += mrg[ln][4][lane];

    float inv = 1.f / fmaxf(denom, 1e-16f);
    ax *= inv; ay *= inv; az *= inv; aw *= inv;
    ax += __shfl_xor(ax,16); ax += __shfl_xor(ax,32);
    ay += __shfl_xor(ay,16); ay += __shfl_xor(ay,32);
    az += __shfl_xor(az,16); az += __shfl_xor(az,32);
    aw += __shfl_xor(aw,16); aw += __shfl_xor(aw,32);
    int d0 = (lane & 15) * 4;
    float4 skv = *reinterpret_cast<const float4*>(sk + n*64 + d0);
    float t0 = ftanh(0.25f*ax + skv.x);
    float t1 = ftanh(0.25f*ay + skv.y);
    float t2 = ftanh(0.25f*az + skv.z);
    float t3 = ftanh(0.25f*aw + skv.w);
    float p8[8];
    #pragma unroll
    for (int j=0;j<8;j++){
        p8[j] = fmaf(t0, Wmlp[(d0+0)*8+j],
                fmaf(t1, Wmlp[(d0+1)*8+j],
                fmaf(t2, Wmlp[(d0+2)*8+j],
                     t3* Wmlp[(d0+3)*8+j])));
    }
    #pragma unroll
    for (int j=0;j<8;j++){
        p8[j] += __shfl_xor(p8[j],1);
        p8[j] += __shfl_xor(p8[j],2);
        p8[j] += __shfl_xor(p8[j],4);
        p8[j] += __shfl_xor(p8[j],8);
    }
    if (lane == 0){
        float4 t0v = {p8[0],p8[1],p8[2],p8[3]};
        float4 t1v = {p8[4],p8[5],p8[6],p8[7]};
        *reinterpret_cast<float4*>(theta + n*8)     = t0v;
        *reinterpret_cast<float4*>(theta + n*8 + 4) = t1v;
        float ab0 = fsig(p8[5]);
        float ab1 = fsig(p8[6]);
        float a  = ab0*ab1;
        float bb = ab0 - a;
        float cc = fsoftplus(p8[7]);
        float4 o0 = {p8[0],p8[1],p8[2],p8[3]};
        float4 o1 = {p8[4],a,bb,cc};
        float* op = out + ((size_t)n*TT + ts)*8;
        *reinterpret_cast<float4*>(op)     = o0;
        *reinterpret_cast<float4*>(op + 4) = o1;
    }
}

// ---------------- K2: packed {qkv(t) || lstm(t+1)} ----------------
// Blocks 0..624: qkv(t) — reads hbuf[t&1] + theta, writes q/sk fp32 and
//   kv fp8 (verbatim r10 phase B, unroll 4 — r6 spill lesson). Skipped
//   when t<0 (prologue).
// Blocks 625..1249: LSTM step s=t+1 — reads hbuf[(s-1)&1] (= hbuf[t&1],
//   concurrent-read-safe) + c, writes hbuf[s&1] + c. Skipped when s>=TT.
// Rationale: lstm(t+1) is independent of qkv(t) (theta only enters qkv),
// so the latency-bound qkv waves and fma-dense lstm waves co-schedule on
// the same SIMDs (m114 overlap). h is double-buffered to avoid the
// concurrent read/write race.
__global__ __launch_bounds__(256) void qkv_lstm_step(
    const float* __restrict__ x,
    const float* __restrict__ W_ih, const float* __restrict__ W_hh,
    const float* __restrict__ b_ih, const float* __restrict__ b_hh,
    float* __restrict__ h0, float* __restrict__ h1,
    float* __restrict__ c,
    const float* __restrict__ theta,
    const float* __restrict__ Wq, const float* __restrict__ bq,
    const float* __restrict__ Wk, const float* __restrict__ bk,
    const float* __restrict__ Wv, const float* __restrict__ bv,
    const float* __restrict__ Wsk, const float* __restrict__ bsk,
    float* __restrict__ q, float* __restrict__ sk,
    unsigned char* __restrict__ kv, int t)
{
    int tid = threadIdx.x;
    if (blockIdx.x < QKV_B){
        // ================= qkv(t) =================
        if (t < 0) return;
        __shared__ float hin[8][72];
        const float* hread = (t & 1) ? h1 : h0;
        int n0 = blockIdx.x * 8;
        for (int i=tid; i<8*72; i+=256){
            int node = i/72, kk = i%72;
            int n = n0 + node;
            hin[node][kk] = (kk<64) ? hread[n*64+kk] : theta[n*8 + (kk-64)];
        }
        __syncthreads();

        if (tid < 208){
            int c4 = tid*4;
            const float* W; const float* b; int ncol; int cc; int kind;
            if (c4 < 256)      { W=Wq;  b=bq;  ncol=256; cc=c4;     kind=0; }
            else if (c4 < 512) { W=Wk;  b=bk;  ncol=256; cc=c4-256; kind=1; }
            else if (c4 < 768) { W=Wv;  b=bv;  ncol=256; cc=c4-512; kind=2; }
            else               { W=Wsk; b=bsk; ncol=64;  cc=c4-768; kind=3; }
            float acc2[8][4];
            #pragma unroll
            for (int nn=0;nn<8;nn++){
                #pragma unroll
                for (int j=0;j<4;j++) acc2[nn][j]=0.f;
            }
            #pragma unroll 4
            for (int kk=0; kk<FIN; kk++){
                float4 w = *reinterpret_cast<const float4*>(W + kk*ncol + cc);
                #pragma unroll
                for (int nn=0;nn<8;nn++){
                    float xv = hin[nn][kk];
                    acc2[nn][0]=fmaf(xv,w.x,acc2[nn][0]);
                    acc2[nn][1]=fmaf(xv,w.y,acc2[nn][1]);
                    acc2[nn][2]=fmaf(xv,w.z,acc2[nn][2]);
                    acc2[nn][3]=fmaf(xv,w.w,acc2[nn][3]);
                }
            }
            float4 bb = *reinterpret_cast<const float4*>(b + cc);
            #pragma unroll
            for (int nn=0;nn<8;nn++){
                int n = n0 + nn;
                float o0=acc2[nn][0]+bb.x, o1=acc2[nn][1]+bb.y;
                float o2=acc2[nn][2]+bb.z, o3=acc2[nn][3]+bb.w;
                if (kind == 0){
                    float4 o = {o0,o1,o2,o3};
                    *reinterpret_cast<float4*>(q + n*NHC + cc) = o;
                } else if (kind == 3){
                    float4 o = {o0,o1,o2,o3};
                    *reinterpret_cast<float4*>(sk + n*64 + cc) = o;
                } else {
                    int pk = __builtin_amdgcn_cvt_pk_fp8_f32(o0, o1, 0,  false);
                    pk     = __builtin_amdgcn_cvt_pk_fp8_f32(o2, o3, pk, true);
                    int off = n*512 + cc*2 + ((kind==2)?4:0);
                    *reinterpret_cast<unsigned int*>(kv + off) = (unsigned int)pk;
                }
            }
        }
    } else {
        // ================= LSTM step s = t+1 =================
        int s = t + 1;
        if (s >= TT) return;
        __shared__ float xh[8][96];
        const float* hread = (s & 1) ? h0 : h1;   // hbuf[(s-1)&1]
        float*       hwrit = (s & 1) ? h1 : h0;   // hbuf[s&1]
        int n0 = (blockIdx.x - QKV_B) * 8;
        for (int i=tid; i<8*96; i+=256){
            int node = i/96, kk = i%96;
            int n = n0 + node;
            xh[node][kk] = (kk<32) ? x[(n*TT + s)*IND + kk] : hread[n*64 + (kk-32)];
        }
        __syncthreads();

        int d  = tid & 63;
        int wv = tid >> 6;
        float acc[2][4];
        #pragma unroll
        for (int p=0;p<2;p++){
            #pragma unroll
            for (int g=0;g<4;g++) acc[p][g]=0.f;
        }
        #pragma unroll 8
        for (int kk=0; kk<32; kk++){
            const float* Wr = W_ih + kk*256;
            float w0=Wr[d], w1=Wr[d+64], w2=Wr[d+128], w3=Wr[d+192];
            float x0 = xh[wv][kk], x1 = xh[wv+4][kk];
            acc[0][0]=fmaf(x0,w0,acc[0][0]); acc[0][1]=fmaf(x0,w1,acc[0][1]);
            acc[0][2]=fmaf(x0,w2,acc[0][2]); acc[0][3]=fmaf(x0,w3,acc[0][3]);
            acc[1][0]=fmaf(x1,w0,acc[1][0]); acc[1][1]=fmaf(x1,w1,acc[1][1]);
            acc[1][2]=fmaf(x1,w2,acc[1][2]); acc[1][3]=fmaf(x1,w3,acc[1][3]);
        }
        #pragma unroll 8
        for (int kk=0; kk<64; kk++){
            const float* Wr = W_hh + kk*256;
            float w0=Wr[d], w1=Wr[d+64], w2=Wr[d+128], w3=Wr[d+192];
            float x0 = xh[wv][32+kk], x1 = xh[wv+4][32+kk];
            acc[0][0]=fmaf(x0,w0,acc[0][0]); acc[0][1]=fmaf(x0,w1,acc[0][1]);
            acc[0][2]=fmaf(x0,w2,acc[0][2]); acc[0][3]=fmaf(x0,w3,acc[0][3]);
            acc[1][0]=fmaf(x1,w0,acc[1][0]); acc[1][1]=fmaf(x1,w1,acc[1][1]);
            acc[1][2]=fmaf(x1,w2,acc[1][2]); acc[1][3]=fmaf(x1,w3,acc[1][3]);
        }
        float bi0 = b_ih[d]     + b_hh[d];
        float bi1 = b_ih[d+64]  + b_hh[d+64];
        float bi2 = b_ih[d+128] + b_hh[d+128];
        float bi3 = b_ih[d+192] + b_hh[d+192];
        #pragma unroll
        for (int p=0;p<2;p++){
            int n = n0 + wv + p*4;
            float gi = fsig (acc[p][0] + bi0);
            float gf = fsig (acc[p][1] + bi1);
            float gg = ftanh(acc[p][2] + bi2);
            float go = fsig (acc[p][3] + bi3);
            float cold = c[n*64 + d];
            float cnew = gf*cold + gi*gg;
            float hnew = go*ftanh(cnew);
            c[n*64 + d] = cnew;
            hwrit[n*64 + d] = hnew;
        }
    }
}

extern "C" void kernel_launch(void* const* d_in, const int* in_sizes, int n_in,
                              void* d_out, int out_size, void* d_ws, size_t ws_size,
                              hipStream_t stream) {
    const float* x     = (const float*)d_in[0];
    const int*   ei    = (const int*)  d_in[1];
    const float* W_ih  = (const float*)d_in[2];
    const float* W_hh  = (const float*)d_in[3];
    const float* b_ih  = (const float*)d_in[4];
    const float* b_hh  = (const float*)d_in[5];
    const float* Wq    = (const float*)d_in[6];
    const float* bq    = (const float*)d_in[7];
    const float* Wk    = (const float*)d_in[8];
    const float* bk    = (const float*)d_in[9];
    const float* Wv    = (const float*)d_in[10];
    const float* bv    = (const float*)d_in[11];
    const float* Wsk   = (const float*)d_in[12];
    const float* bsk   = (const float*)d_in[13];
    const float* Wmlp  = (const float*)d_in[14];
    float* out = (float*)d_out;

    // workspace layout (16B-aligned sections)
    float* f = (float*)d_ws;
    float* h0    = f;                    // N*64  (h after even lstm steps)
    float* h1    = h0 + NN*64;           // N*64  (h after odd lstm steps)
    float* c     = h1 + NN*64;           // N*64
    float* theta = c + NN*64;            // N*8
    float* q     = theta + NN*8;         // N*256
    float* skb   = q + NN*NHC;           // N*64
    unsigned char* kvb = (unsigned char*)(skb + NN*64);    // N*512 bytes fp8
    int* ip      = (int*)(kvb + (size_t)NN*512);
    int* row_ptr = ip;                   // N+1
    int* cnt     = row_ptr + (NN+1);     // N
    int* cursor  = cnt + NN;             // N
    int* colv    = cursor + NN;          // E

    const int* src = ei;
    const int* dst = ei + EE;

    // zero h0,h1,c,theta (contiguous) and counts
    hipMemsetAsync(h0, 0, (size_t)NN*(64+64+64+8)*sizeof(float), stream);
    hipMemsetAsync(cnt, 0, (size_t)NN*sizeof(int), stream);

    count_edges<<<(EE+255)/256, 256, 0, stream>>>(dst, cnt);
    scan_csr<<<1, 1024, 0, stream>>>(cnt, row_ptr, cursor);
    fill_edges<<<(EE+255)/256, 256, 0, stream>>>(src, dst, cursor, colv);

    // prologue: lstm(0) only (t=-1 -> qkv skipped, s=0)
    qkv_lstm_step<<<QKV_B + LSTM_B, 256, 0, stream>>>(
        x, W_ih, W_hh, b_ih, b_hh, h0, h1, c, theta,
        Wq,bq, Wk,bk, Wv,bv, Wsk,bsk, q, skb, kvb, -1);

    for (int t=0; t<TT; t++){
        if (t >= 1)
            attn_step<<<NN/2, 256, 0, stream>>>(q, kvb, skb, row_ptr, colv,
                                                Wmlp, theta, out, t-1);
        qkv_lstm_step<<<QKV_B + LSTM_B, 256, 0, stream>>>(
            x, W_ih, W_hh, b_ih, b_hh, h0, h1, c, theta,
            Wq,bq, Wk,bk, Wv,bv, Wsk,bsk, q, skb, kvb, t);
    }
    attn_step<<<NN/2, 256, 0, stream>>>(q, kvb, skb, row_ptr, colv,
                                        Wmlp, theta, out, TT-1);
}

// Round 14
// 4910.409 us; speedup vs baseline: 1.0332x; 1.0332x over previous
//
#include <hip/hip_runtime.h>
#include <math.h>

#define NN 5000
#define TT 100
#define IND 32
#define FEATD 64
#define HIDD 64
#define OUTD 8
#define NHEADS 4
#define EE 160000
#define FIN 72
#define NHC 256     // HEADS*HID
#define ATTN_B 2500 // NN/2 fused attn+qkv blocks
#define LSTM_B 625  // NN/8 lstm blocks

typedef float floatx2 __attribute__((ext_vector_type(2)));

__device__ __forceinline__ float fsig(float x){ return 1.f/(1.f+__expf(-x)); }
__device__ __forceinline__ float ftanh(float x){ return 1.f - 2.f/(__expf(2.f*x)+1.f); }
__device__ __forceinline__ float fsoftplus(float x){ return (x>20.f)? x : log1pf(__expf(x)); }

// ---------------- CSR build ----------------
__global__ __launch_bounds__(256) void count_edges(const int* __restrict__ dst,
                                                   int* __restrict__ cnt){
    int e = blockIdx.x*256 + threadIdx.x;
    if (e < EE) atomicAdd(&cnt[dst[e]], 1);
}

#define SCAN_N 5120
__global__ __launch_bounds__(1024) void scan_csr(const int* __restrict__ cnt,
                                                 int* __restrict__ row_ptr,
                                                 int* __restrict__ cursor){
    __shared__ int sa[SCAN_N];
    __shared__ int sb[SCAN_N];
    int tid = threadIdx.x;
    for (int i=tid;i<SCAN_N;i+=1024) sa[i] = (i<NN)?cnt[i]:0;
    __syncthreads();
    int *s=sa, *d=sb;
    for (int off=1; off<SCAN_N; off<<=1){
        for (int i=tid;i<SCAN_N;i+=1024){
            int v = s[i];
            if (i>=off) v += s[i-off];
            d[i] = v;
        }
        __syncthreads();
        int* t=s; s=d; d=t;
    }
    for (int i=tid;i<=NN;i+=1024){
        int excl = (i==0)?0:s[i-1];
        row_ptr[i] = excl;
        if (i<NN) cursor[i] = excl;
    }
}

__global__ __launch_bounds__(256) void fill_edges(const int* __restrict__ src,
                                                  const int* __restrict__ dst,
                                                  int* __restrict__ cursor,
                                                  int* __restrict__ col){
    int e = blockIdx.x*256 + threadIdx.x;
    if (e < EE){
        int dn = dst[e];
        int pos = atomicAdd(&cursor[dn], 1);
        col[pos] = src[e];
    }
}

// ================== THE fused per-step kernel ==================
// Launch t (t=-1 prologue .. TT-1):
//  Blocks 0..2499 (2 nodes each, 4 waves):
//    Phase 1 (t>=1): attn(t-1) — dual no-max fp8 chains, 2 waves/node;
//      epilogue writes out(t-1); theta(t) goes to LDS only.
//    Phase 2 (t>=0): qkv(t) for the SAME 2 nodes — reads hbuf[t&1] + LDS
//      theta, writes q/sk fp32 and kvw=kvbuf[t&1] fp8. Same-block ordering
//      makes q/sk single-buffer safe; kv is DOUBLE-buffered because attn
//      gathers other blocks' rows.
//  Blocks 2500..3124: lstm(t+1) — reads hbuf[t&1]+c, writes hbuf[(t+1)&1]+c.
// R13 crash root-cause (fixed here): the lstm h-staging evaluated
// hread[n*64+(kk-32)] for kk<32 (negative offset -> OOB before d_ws).
// Guard must be on kk, not only on s.
#define LOADKV(e) (*reinterpret_cast<const uint2*>(kvr + (size_t)col[(e)]*512 + lane*8))
__global__ __launch_bounds__(256) void step_kernel(
    const float* __restrict__ x,
    const float* __restrict__ W_ih, const float* __restrict__ W_hh,
    const float* __restrict__ b_ih, const float* __restrict__ b_hh,
    float* __restrict__ h0, float* __restrict__ h1,
    float* __restrict__ c,
    const float* __restrict__ Wq, const float* __restrict__ bq,
    const float* __restrict__ Wk, const float* __restrict__ bk,
    const float* __restrict__ Wv, const float* __restrict__ bv,
    const float* __restrict__ Wsk, const float* __restrict__ bsk,
    float* __restrict__ q, float* __restrict__ sk,
    const unsigned char* __restrict__ kvr,   // attn reads kvbuf[(t-1)&1]
    unsigned char* __restrict__ kvw,         // qkv writes kvbuf[t&1]
    const int* __restrict__ row_ptr,
    const int* __restrict__ col,
    const float* __restrict__ Wmlp,
    float* __restrict__ out,
    int t)
{
    int tid = threadIdx.x;
    if (blockIdx.x < ATTN_B){
        if (t < 0) return;                     // prologue: nothing here
        __shared__ float mrg[2][5][64];
        __shared__ float hin[2][FIN];
        int wvid = tid >> 6;
        int lane = tid & 63;
        int ln   = wvid >> 1;
        int half = wvid & 1;
        int n = blockIdx.x*2 + ln;

        // stage h(t) early (loads land under attn compute)
        const float* hread = (t & 1) ? h1 : h0;
        for (int i=tid; i<2*64; i+=256){
            int node = i>>6, kk = i&63;
            hin[node][kk] = hread[(blockIdx.x*2+node)*64 + kk];
        }
        if (t == 0){
            if (tid < 16){ int node=tid>>3, j=tid&7; hin[node][64+j] = 0.f; }
        }

        float denom, ax, ay, az, aw;   // half0 merged state
        if (t >= 1){
            int e0 = row_ptr[n], e1 = row_ptr[n+1];
            float4 qv = *reinterpret_cast<const float4*>(q + n*NHC + lane*4);
            qv.x *= 0.125f; qv.y *= 0.125f; qv.z *= 0.125f; qv.w *= 0.125f;

            float denA=0.f, denB=0.f;
            float aA0=0.f, aA1=0.f, aA2=0.f, aA3=0.f;
            float aB0=0.f, aB1=0.f, aB2=0.f, aB3=0.f;
            const uint2 zv = {0u,0u};
            uint2 bA0=zv, bA1=zv, bB0=zv, bB1=zv;
            int base = e0 + half;
            if (base     < e1) bA0 = LOADKV(base);
            if (base + 2 < e1) bB0 = LOADKV(base+2);
            if (base + 4 < e1) bA1 = LOADKV(base+4);
            if (base + 6 < e1) bB1 = LOADKV(base+6);
            for (int e = base; e < e1; e += 4){
                uint2 uA = bA0; bA0 = bA1; bA1 = zv;
                uint2 uB = bB0; bB0 = bB1; bB1 = zv;
                if (e + 8  < e1) bA1 = LOADKV(e+8);
                if (e + 10 < e1) bB1 = LOADKV(e+10);

                floatx2 kA0 = __builtin_amdgcn_cvt_pk_f32_fp8(uA.x, false);
                floatx2 kA1 = __builtin_amdgcn_cvt_pk_f32_fp8(uA.x, true);
                floatx2 kB0 = __builtin_amdgcn_cvt_pk_f32_fp8(uB.x, false);
                floatx2 kB1 = __builtin_amdgcn_cvt_pk_f32_fp8(uB.x, true);
                float pA = qv.x*kA0[0] + qv.y*kA0[1] + qv.z*kA1[0] + qv.w*kA1[1];
                float pB = qv.x*kB0[0] + qv.y*kB0[1] + qv.z*kB1[0] + qv.w*kB1[1];
                pA += __shfl_xor(pA,1); pB += __shfl_xor(pB,1);
                pA += __shfl_xor(pA,2); pB += __shfl_xor(pB,2);
                pA += __shfl_xor(pA,4); pB += __shfl_xor(pB,4);
                pA += __shfl_xor(pA,8); pB += __shfl_xor(pB,8);

                float eA = __expf(pA);
                float eB = __expf((e + 2 < e1) ? pB : -INFINITY);
                floatx2 vA0 = __builtin_amdgcn_cvt_pk_f32_fp8(uA.y, false);
                floatx2 vA1 = __builtin_amdgcn_cvt_pk_f32_fp8(uA.y, true);
                floatx2 vB0 = __builtin_amdgcn_cvt_pk_f32_fp8(uB.y, false);
                floatx2 vB1 = __builtin_amdgcn_cvt_pk_f32_fp8(uB.y, true);
                denA += eA;
                aA0 = fmaf(eA, vA0[0], aA0);
                aA1 = fmaf(eA, vA0[1], aA1);
                aA2 = fmaf(eA, vA1[0], aA2);
                aA3 = fmaf(eA, vA1[1], aA3);
                denB += eB;
                aB0 = fmaf(eB, vB0[0], aB0);
                aB1 = fmaf(eB, vB0[1], aB1);
                aB2 = fmaf(eB, vB1[0], aB2);
                aB3 = fmaf(eB, vB1[1], aB3);
            }
            denom = denA + denB;
            ax = aA0 + aB0; ay = aA1 + aB1;
            az = aA2 + aB2; aw = aA3 + aB3;
            if (half == 1){
                mrg[ln][0][lane]=denom;
                mrg[ln][1][lane]=ax; mrg[ln][2][lane]=ay;
                mrg[ln][3][lane]=az; mrg[ln][4][lane]=aw;
            }
        }
        __syncthreads();
        if (t >= 1 && half == 0){
            denom += mrg[ln][0][lane];
            ax += mrg[ln][1][lane];
            ay += mrg[ln][2][lane];
            az += mrg[ln][3][lane];
            aw += mrg[ln][4][lane];
            float inv = 1.f / fmaxf(denom, 1e-16f);
            ax *= inv; ay *= inv; az *= inv; aw *= inv;
            ax += __shfl_xor(ax,16); ax += __shfl_xor(ax,32);
            ay += __shfl_xor(ay,16); ay += __shfl_xor(ay,32);
            az += __shfl_xor(az,16); az += __shfl_xor(az,32);
            aw += __shfl_xor(aw,16); aw += __shfl_xor(aw,32);
            int d0 = (lane & 15) * 4;
            float4 skv = *reinterpret_cast<const float4*>(sk + n*64 + d0);
            float t0 = ftanh(0.25f*ax + skv.x);
            float t1 = ftanh(0.25f*ay + skv.y);
            float t2 = ftanh(0.25f*az + skv.z);
            float t3 = ftanh(0.25f*aw + skv.w);
            float p8[8];
            #pragma unroll
            for (int j=0;j<8;j++){
                p8[j] = fmaf(t0, Wmlp[(d0+0)*8+j],
                        fmaf(t1, Wmlp[(d0+1)*8+j],
                        fmaf(t2, Wmlp[(d0+2)*8+j],
                             t3* Wmlp[(d0+3)*8+j])));
            }
            #pragma unroll
            for (int j=0;j<8;j++){
                p8[j] += __shfl_xor(p8[j],1);
                p8[j] += __shfl_xor(p8[j],2);
                p8[j] += __shfl_xor(p8[j],4);
                p8[j] += __shfl_xor(p8[j],8);
            }
            if (lane == 0){
                #pragma unroll
                for (int j=0;j<8;j++) hin[ln][64+j] = p8[j];  // theta(t) -> LDS
                float ab0 = fsig(p8[5]);
                float ab1 = fsig(p8[6]);
                float a  = ab0*ab1;
                float bb = ab0 - a;
                float cc = fsoftplus(p8[7]);
                float4 o0 = {p8[0],p8[1],p8[2],p8[3]};
                float4 o1 = {p8[4],a,bb,cc};
                float* op = out + ((size_t)n*TT + (t-1))*8;
                *reinterpret_cast<float4*>(op)     = o0;
                *reinterpret_cast<float4*>(op + 4) = o1;
            }
        }
        __syncthreads();

        // ---- Phase 2: qkv(t) for the block's 2 nodes ----
        if (tid < 208){
            int c4 = tid*4;
            const float* W; const float* b; int ncol; int cc; int kind;
            if (c4 < 256)      { W=Wq;  b=bq;  ncol=256; cc=c4;     kind=0; }
            else if (c4 < 512) { W=Wk;  b=bk;  ncol=256; cc=c4-256; kind=1; }
            else if (c4 < 768) { W=Wv;  b=bv;  ncol=256; cc=c4-512; kind=2; }
            else               { W=Wsk; b=bsk; ncol=64;  cc=c4-768; kind=3; }
            float acc2[2][4];
            #pragma unroll
            for (int nn=0;nn<2;nn++){
                #pragma unroll
                for (int j=0;j<4;j++) acc2[nn][j]=0.f;
            }
            #pragma unroll 4
            for (int kk=0; kk<FIN; kk++){
                float4 w = *reinterpret_cast<const float4*>(W + kk*ncol + cc);
                #pragma unroll
                for (int nn=0;nn<2;nn++){
                    float xv = hin[nn][kk];
                    acc2[nn][0]=fmaf(xv,w.x,acc2[nn][0]);
                    acc2[nn][1]=fmaf(xv,w.y,acc2[nn][1]);
                    acc2[nn][2]=fmaf(xv,w.z,acc2[nn][2]);
                    acc2[nn][3]=fmaf(xv,w.w,acc2[nn][3]);
                }
            }
            float4 bb = *reinterpret_cast<const float4*>(b + cc);
            #pragma unroll
            for (int nn=0;nn<2;nn++){
                int n2 = blockIdx.x*2 + nn;
                float o0=acc2[nn][0]+bb.x, o1=acc2[nn][1]+bb.y;
                float o2=acc2[nn][2]+bb.z, o3=acc2[nn][3]+bb.w;
                if (kind == 0){
                    float4 o = {o0,o1,o2,o3};
                    *reinterpret_cast<float4*>(q + n2*NHC + cc) = o;
                } else if (kind == 3){
                    float4 o = {o0,o1,o2,o3};
                    *reinterpret_cast<float4*>(sk + n2*64 + cc) = o;
                } else {
                    int pk = __builtin_amdgcn_cvt_pk_fp8_f32(o0, o1, 0,  false);
                    pk     = __builtin_amdgcn_cvt_pk_fp8_f32(o2, o3, pk, true);
                    int off = n2*512 + cc*2 + ((kind==2)?4:0);
                    *reinterpret_cast<unsigned int*>(kvw + off) = (unsigned int)pk;
                }
            }
        }
    } else {
        // ================= LSTM step s = t+1 =================
        int s = t + 1;
        if (s >= TT) return;
        __shared__ float xh[8][96];
        const float* hread = (s & 1) ? h0 : h1;   // hbuf[(s-1)&1]
        float*       hwrit = (s & 1) ? h1 : h0;   // hbuf[s&1]
        int n0 = (blockIdx.x - ATTN_B) * 8;
        for (int i=tid; i<8*96; i+=256){
            int node = i/96, kk = i%96;
            int n = n0 + node;
            // guard OOB: hread only touched when kk>=32 (r13 crash fix)
            xh[node][kk] = (kk<32) ? x[(n*TT + s)*IND + kk]
                                   : ((s == 0) ? 0.f : hread[n*64 + (kk-32)]);
        }
        __syncthreads();

        int d  = tid & 63;
        int wv = tid >> 6;
        float acc[2][4];
        #pragma unroll
        for (int p=0;p<2;p++){
            #pragma unroll
            for (int g=0;g<4;g++) acc[p][g]=0.f;
        }
        #pragma unroll 8
        for (int kk=0; kk<32; kk++){
            const float* Wr = W_ih + kk*256;
            float w0=Wr[d], w1=Wr[d+64], w2=Wr[d+128], w3=Wr[d+192];
            float x0 = xh[wv][kk], x1 = xh[wv+4][kk];
            acc[0][0]=fmaf(x0,w0,acc[0][0]); acc[0][1]=fmaf(x0,w1,acc[0][1]);
            acc[0][2]=fmaf(x0,w2,acc[0][2]); acc[0][3]=fmaf(x0,w3,acc[0][3]);
            acc[1][0]=fmaf(x1,w0,acc[1][0]); acc[1][1]=fmaf(x1,w1,acc[1][1]);
            acc[1][2]=fmaf(x1,w2,acc[1][2]); acc[1][3]=fmaf(x1,w3,acc[1][3]);
        }
        #pragma unroll 8
        for (int kk=0; kk<64; kk++){
            const float* Wr = W_hh + kk*256;
            float w0=Wr[d], w1=Wr[d+64], w2=Wr[d+128], w3=Wr[d+192];
            float x0 = xh[wv][32+kk], x1 = xh[wv+4][32+kk];
            acc[0][0]=fmaf(x0,w0,acc[0][0]); acc[0][1]=fmaf(x0,w1,acc[0][1]);
            acc[0][2]=fmaf(x0,w2,acc[0][2]); acc[0][3]=fmaf(x0,w3,acc[0][3]);
            acc[1][0]=fmaf(x1,w0,acc[1][0]); acc[1][1]=fmaf(x1,w1,acc[1][1]);
            acc[1][2]=fmaf(x1,w2,acc[1][2]); acc[1][3]=fmaf(x1,w3,acc[1][3]);
        }
        float bi0 = b_ih[d]     + b_hh[d];
        float bi1 = b_ih[d+64]  + b_hh[d+64];
        float bi2 = b_ih[d+128] + b_hh[d+128];
        float bi3 = b_ih[d+192] + b_hh[d+192];
        #pragma unroll
        for (int p=0;p<2;p++){
            int n = n0 + wv + p*4;
            float gi = fsig (acc[p][0] + bi0);
            float gf = fsig (acc[p][1] + bi1);
            float gg = ftanh(acc[p][2] + bi2);
            float go = fsig (acc[p][3] + bi3);
            float cold = (s == 0) ? 0.f : c[n*64 + d];
            float cnew = gf*cold + gi*gg;
            float hnew = go*ftanh(cnew);
            c[n*64 + d] = cnew;
            hwrit[n*64 + d] = hnew;
        }
    }
}

// ---------------- epilogue attn (step TT-1) ----------------
#define LOADKV2(e) (*reinterpret_cast<const uint2*>(kv + (size_t)col[(e)]*512 + lane*8))
__global__ __launch_bounds__(256) void attn_final(
    const float* __restrict__ q,
    const unsigned char* __restrict__ kv,
    const float* __restrict__ sk,
    const int* __restrict__ row_ptr,
    const int* __restrict__ col,
    const float* __restrict__ Wmlp,
    float* __restrict__ out)
{
    __shared__ float mrg[2][5][64];
    int tid = threadIdx.x;
    int wvid = tid >> 6;
    int lane = tid & 63;
    int ln   = wvid >> 1;
    int half = wvid & 1;
    int n = blockIdx.x*2 + ln;
    int e0 = row_ptr[n], e1 = row_ptr[n+1];
    float4 qv = *reinterpret_cast<const float4*>(q + n*NHC + lane*4);
    qv.x *= 0.125f; qv.y *= 0.125f; qv.z *= 0.125f; qv.w *= 0.125f;

    float denA=0.f, denB=0.f;
    float aA0=0.f, aA1=0.f, aA2=0.f, aA3=0.f;
    float aB0=0.f, aB1=0.f, aB2=0.f, aB3=0.f;
    const uint2 zv = {0u,0u};
    uint2 bA0=zv, bA1=zv, bB0=zv, bB1=zv;
    int base = e0 + half;
    if (base     < e1) bA0 = LOADKV2(base);
    if (base + 2 < e1) bB0 = LOADKV2(base+2);
    if (base + 4 < e1) bA1 = LOADKV2(base+4);
    if (base + 6 < e1) bB1 = LOADKV2(base+6);
    for (int e = base; e < e1; e += 4){
        uint2 uA = bA0; bA0 = bA1; bA1 = zv;
        uint2 uB = bB0; bB0 = bB1; bB1 = zv;
        if (e + 8  < e1) bA1 = LOADKV2(e+8);
        if (e + 10 < e1) bB1 = LOADKV2(e+10);
        floatx2 kA0 = __builtin_amdgcn_cvt_pk_f32_fp8(uA.x, false);
        floatx2 kA1 = __builtin_amdgcn_cvt_pk_f32_fp8(uA.x, true);
        floatx2 kB0 = __builtin_amdgcn_cvt_pk_f32_fp8(uB.x, false);
        floatx2 kB1 = __builtin_amdgcn_cvt_pk_f32_fp8(uB.x, true);
        float pA = qv.x*kA0[0] + qv.y*kA0[1] + qv.z*kA1[0] + qv.w*kA1[1];
        float pB = qv.x*kB0[0] + qv.y*kB0[1] + qv.z*kB1[0] + qv.w*kB1[1];
        pA += __shfl_xor(pA,1); pB += __shfl_xor(pB,1);
        pA += __shfl_xor(pA,2); pB += __shfl_xor(pB,2);
        pA += __shfl_xor(pA,4); pB += __shfl_xor(pB,4);
        pA += __shfl_xor(pA,8); pB += __shfl_xor(pB,8);
        float eA = __expf(pA);
        float eB = __expf((e + 2 < e1) ? pB : -INFINITY);
        floatx2 vA0 = __builtin_amdgcn_cvt_pk_f32_fp8(uA.y, false);
        floatx2 vA1 = __builtin_amdgcn_cvt_pk_f32_fp8(uA.y, true);
        floatx2 vB0 = __builtin_amdgcn_cvt_pk_f32_fp8(uB.y, false);
        floatx2 vB1 = __builtin_amdgcn_cvt_pk_f32_fp8(uB.y, true);
        denA += eA;
        aA0 = fmaf(eA, vA0[0], aA0);
        aA1 = fmaf(eA, vA0[1], aA1);
        aA2 = fmaf(eA, vA1[0], aA2);
        aA3 = fmaf(eA, vA1[1], aA3);
        denB += eB;
        aB0 = fmaf(eB, vB0[0], aB0);
        aB1 = fmaf(eB, vB0[1], aB1);
        aB2 = fmaf(eB, vB1[0], aB2);
        aB3 = fmaf(eB, vB1[1], aB3);
    }
    float denom = denA + denB;
    float ax = aA0 + aB0;
    float ay = aA1 + aB1;
    float az = aA2 + aB2;
    float aw = aA3 + aB3;
    if (half == 1){
        mrg[ln][0][lane]=denom;
        mrg[ln][1][lane]=ax; mrg[ln][2][lane]=ay;
        mrg[ln][3][lane]=az; mrg[ln][4][lane]=aw;
    }
    __syncthreads();
    if (half == 1) return;
    denom += mrg[ln][0][lane];
    ax += mrg[ln][1][lane];
    ay += mrg[ln][2][lane];
    az += mrg[ln][3][lane];
    aw += mrg[ln][4][lane];
    float inv = 1.f / fmaxf(denom, 1e-16f);
    ax *= inv; ay *= inv; az *= inv; aw *= inv;
    ax += __shfl_xor(ax,16); ax += __shfl_xor(ax,32);
    ay += __shfl_xor(ay,16); ay += __shfl_xor(ay,32);
    az += __shfl_xor(az,16); az += __shfl_xor(az,32);
    aw += __shfl_xor(aw,16); aw += __shfl_xor(aw,32);
    int d0 = (lane & 15) * 4;
    float4 skv = *reinterpret_cast<const float4*>(sk + n*64 + d0);
    float t0 = ftanh(0.25f*ax + skv.x);
    float t1 = ftanh(0.25f*ay + skv.y);
    float t2 = ftanh(0.25f*az + skv.z);
    float t3 = ftanh(0.25f*aw + skv.w);
    float p8[8];
    #pragma unroll
    for (int j=0;j<8;j++){
        p8[j] = fmaf(t0, Wmlp[(d0+0)*8+j],
                fmaf(t1, Wmlp[(d0+1)*8+j],
                fmaf(t2, Wmlp[(d0+2)*8+j],
                     t3* Wmlp[(d0+3)*8+j])));
    }
    #pragma unroll
    for (int j=0;j<8;j++){
        p8[j] += __shfl_xor(p8[j],1);
        p8[j] += __shfl_xor(p8[j],2);
        p8[j] += __shfl_xor(p8[j],4);
        p8[j] += __shfl_xor(p8[j],8);
    }
    if (lane == 0){
        float ab0 = fsig(p8[5]);
        float ab1 = fsig(p8[6]);
        float a  = ab0*ab1;
        float bb = ab0 - a;
        float cc = fsoftplus(p8[7]);
        float4 o0 = {p8[0],p8[1],p8[2],p8[3]};
        float4 o1 = {p8[4],a,bb,cc};
        float* op = out + ((size_t)n*TT + (TT-1))*8;
        *reinterpret_cast<float4*>(op)     = o0;
        *reinterpret_cast<float4*>(op + 4) = o1;
    }
}

extern "C" void kernel_launch(void* const* d_in, const int* in_sizes, int n_in,
                              void* d_out, int out_size, void* d_ws, size_t ws_size,
                              hipStream_t stream) {
    const float* x     = (const float*)d_in[0];
    const int*   ei    = (const int*)  d_in[1];
    const float* W_ih  = (const float*)d_in[2];
    const float* W_hh  = (const float*)d_in[3];
    const float* b_ih  = (const float*)d_in[4];
    const float* b_hh  = (const float*)d_in[5];
    const float* Wq    = (const float*)d_in[6];
    const float* bq    = (const float*)d_in[7];
    const float* Wk    = (const float*)d_in[8];
    const float* bk    = (const float*)d_in[9];
    const float* Wv    = (const float*)d_in[10];
    const float* bv    = (const float*)d_in[11];
    const float* Wsk   = (const float*)d_in[12];
    const float* bsk   = (const float*)d_in[13];
    const float* Wmlp  = (const float*)d_in[14];
    float* out = (float*)d_out;

    // workspace layout (16B-aligned sections)
    float* f = (float*)d_ws;
    float* h0    = f;                    // N*64
    float* h1    = h0 + NN*64;           // N*64
    float* c     = h1 + NN*64;           // N*64
    float* q     = c + NN*64;            // N*256
    float* skb   = q + NN*NHC;           // N*64
    unsigned char* kvb0 = (unsigned char*)(skb + NN*64);   // N*512 bytes fp8
    unsigned char* kvb1 = kvb0 + (size_t)NN*512;           // N*512 bytes fp8
    int* ip      = (int*)(kvb1 + (size_t)NN*512);
    int* row_ptr = ip;                   // N+1
    int* cnt     = row_ptr + (NN+1);     // N
    int* cursor  = cnt + NN;             // N
    int* colv    = cursor + NN;          // E

    const int* src = ei;
    const int* dst = ei + EE;

    hipMemsetAsync(cnt, 0, (size_t)NN*sizeof(int), stream);

    count_edges<<<(EE+255)/256, 256, 0, stream>>>(dst, cnt);
    scan_csr<<<1, 1024, 0, stream>>>(cnt, row_ptr, cursor);
    fill_edges<<<(EE+255)/256, 256, 0, stream>>>(src, dst, cursor, colv);

    // t = -1 prologue (lstm(0) only) .. t = TT-1
    for (int t=-1; t<TT; t++){
        const unsigned char* kvr = ((t-1) & 1) ? kvb1 : kvb0;
        unsigned char*       kvw = (t & 1) ? kvb1 : kvb0;
        step_kernel<<<ATTN_B + LSTM_B, 256, 0, stream>>>(
            x, W_ih, W_hh, b_ih, b_hh, h0, h1, c,
            Wq,bq, Wk,bk, Wv,bv, Wsk,bsk,
            q, skb, kvr, kvw, row_ptr, colv, Wmlp, out, t);
    }
    attn_final<<<NN/2, 256, 0, stream>>>(q, ((TT-1)&1)?kvb1:kvb0, skb,
                                         row_ptr, colv, Wmlp, out);
}